// Round 4
// baseline (77.310 us; speedup 1.0000x reference)
//
#include <hip/hip_runtime.h>
#include <hip/hip_bf16.h>
#include <math.h>

// ---------------------------------------------------------------------------
// NTXentLoss fused, symmetric triangle, uniform-tile version.
// loss = mean(lse(logits) - picked), logits = G G^T, G = sqrt(2)*f/||f||.
// 2080 blocks, one 128x128 tile (rb,cb), cb<=rb, each. Tile contributes
// exp-row-sums to prow[cb][panel rb] and (off-diag) exp-col-sums to
// pcol[2rb+wr][panel cb]. All slots writer-unique -> no atomics, no init.
// A panel -> registers via direct global loads (no LDS, no barrier);
// B panel staged in 64 KB LDS via global_load_lds (XOR-swizzled source).
// picked[i<B] = 2 exactly; picked[i>=B] computed fp32 at normalize time.
// ---------------------------------------------------------------------------

#define B_ROWS 4096
#define D_DIM  256
#define N_ROWS 8192
#define NPANEL 64            // 8192 / 128 panels
#define NTRI   2080          // 64*65/2 = 8*260 (XCD-bijective)

typedef __attribute__((ext_vector_type(8))) short short8;
typedef __attribute__((ext_vector_type(4))) float f32x4;

// ---------------- kernel 1: normalize (fp32->bf16) + picked ----------------
__global__ __launch_bounds__(256) void nt_norm_picked(
    const float* __restrict__ f1, const float* __restrict__ f2,
    unsigned short* __restrict__ G, float* __restrict__ picked_cross) {
  __shared__ float4 vbuf[2][64];
  __shared__ float ssbuf[2];
  const int tid = threadIdx.x, lane = tid & 63, w = tid >> 6;
  const int pl = w >> 1, src = w & 1;
  const int p = blockIdx.x * 2 + pl;               // pair index 0..B-1
  const float* rowp = (src == 0 ? f1 : f2) + (size_t)p * D_DIM;
  float4 v = reinterpret_cast<const float4*>(rowp)[lane];
  float ss = v.x * v.x + v.y * v.y + v.z * v.z + v.w * v.w;
#pragma unroll
  for (int m = 1; m < 64; m <<= 1) ss += __shfl_xor(ss, m, 64);
  const float scale = 1.41421356237309515f * rsqrtf(fmaxf(ss, 1e-30f));
  union { ushort4 u; __hip_bfloat16 h[4]; } pk;
  pk.h[0] = __float2bfloat16(v.x * scale);
  pk.h[1] = __float2bfloat16(v.y * scale);
  pk.h[2] = __float2bfloat16(v.z * scale);
  pk.h[3] = __float2bfloat16(v.w * scale);
  const int grow = p + src * B_ROWS;
  reinterpret_cast<ushort4*>(G + (size_t)grow * D_DIM)[lane] = pk.u;
  if (src == 0) { vbuf[pl][lane] = v; if (lane == 0) ssbuf[pl] = ss; }
  __syncthreads();
  if (src == 1) {
    float4 u = vbuf[pl][lane];
    float d = v.x * u.x + v.y * u.y + v.z * u.z + v.w * u.w;
#pragma unroll
    for (int m = 1; m < 64; m <<= 1) d += __shfl_xor(d, m, 64);
    if (lane == 0)
      picked_cross[p] = 2.0f * d * rsqrtf(ss) * rsqrtf(ssbuf[pl]);
  }
}

// ------------- staging helper: contiguous global -> LDS, swizzled ----------
// LDS[o] = G[base + swz(o)], swz(o) = o ^ (((o>>9)&7)<<4)  (row stride 512 B).
__device__ __forceinline__ void stage_lds(const char* gsrc_base, char* lds_base,
                                          int rounds, int tid) {
  const int lane = tid & 63, wid = tid >> 6;
  for (int r = 0; r < rounds; ++r) {
    const int o  = r * 4096 + wid * 1024 + lane * 16;
    const int so = o ^ (((o >> 9) & 7) << 4);
    __builtin_amdgcn_global_load_lds(
        (const __attribute__((address_space(1))) void*)(gsrc_base + so),
        (__attribute__((address_space(3))) void*)(lds_base + r * 4096 + wid * 1024),
        16, 0, 0);
  }
}

// ---------- kernel 2: one 128x128 tile + fused exp row/col sums ------------
// block 256 (4 waves, 2x2), wave tile 64x64 (n processed in 2 col-halves).
__global__ __launch_bounds__(256, 2) void nt_gemm_tile(
    const unsigned short* __restrict__ G,
    float* __restrict__ prow,   // [NPANEL][N_ROWS]
    float* __restrict__ pcol)   // [2*NPANEL][N_ROWS]
{
  // XCD-contiguous remap (bijective: NTRI = 8*260), then triangular decode.
  const int bid = (blockIdx.x & 7) * (NTRI / 8) + (blockIdx.x >> 3);
  int rb = (int)((sqrtf(8.f * (float)bid + 1.f) - 1.f) * 0.5f);
  while ((rb + 1) * (rb + 2) / 2 <= bid) ++rb;
  while (rb * (rb + 1) / 2 > bid) --rb;
  const int cb = bid - rb * (rb + 1) / 2;

  const int tid  = threadIdx.x;
  const int lane = tid & 63;
  const int wid  = tid >> 6;
  const int wr   = wid >> 1;         // row half (64 rows)
  const int wc   = wid & 1;          // col half (64 cols)

  __shared__ short8 lds8[4096];      // 64 KB: B panel
  char* ldsb = reinterpret_cast<char*>(lds8);
  const char* gb = reinterpret_cast<const char*>(G);

  // ---- stage B panel (rows cb*128..+128, 64 KB) into LDS (async) ----
  stage_lds(gb + (size_t)cb * 65536, ldsb, 16, tid);

  // ---- A fragments: direct global -> registers (L2 hits, no LDS) ----
  short8 afrag[4][8];
  {
    const int r0 = rb * 128 + wr * 64;
    const int q16 = (lane >> 4) << 4;
#pragma unroll
    for (int m = 0; m < 4; ++m) {
      const size_t rowoff = (size_t)(r0 + m * 16 + (lane & 15)) * 512;
#pragma unroll
      for (int ks = 0; ks < 8; ++ks)
        afrag[m][ks] = *reinterpret_cast<const short8*>(gb + rowoff + ks * 64 + q16);
    }
  }
  __syncthreads();                   // B panel resident (drains LDS-DMA)

  float rs[16];
#pragma unroll
  for (int i = 0; i < 16; ++i) rs[i] = 0.f;

#pragma unroll
  for (int nh = 0; nh < 2; ++nh) {   // two 32-col halves of this wave's 64
    f32x4 acc[4][2] = {};
#pragma unroll
    for (int ks = 0; ks < 8; ++ks) {
      short8 bfrag[2];
#pragma unroll
      for (int n = 0; n < 2; ++n) {
        const int brow = wc * 64 + nh * 32 + n * 16 + (lane & 15);
        const int off  = (brow * 512 + ks * 64 + ((lane >> 4) << 4)) ^ ((brow & 7) << 4);
        bfrag[n] = *reinterpret_cast<const short8*>(ldsb + off);
      }
#pragma unroll
      for (int m = 0; m < 4; ++m)
#pragma unroll
        for (int n = 0; n < 2; ++n)
          acc[m][n] = __builtin_amdgcn_mfma_f32_16x16x32_bf16(
              afrag[m][ks], bfrag[n], acc[m][n], 0, 0, 0);
    }
    // exp: rows accumulate into rs; col sums reduced over rows and stored
    float cs0 = 0.f, cs1 = 0.f;
#pragma unroll
    for (int m = 0; m < 4; ++m)
#pragma unroll
      for (int j = 0; j < 4; ++j) {
        const float e0 = __expf(acc[m][0][j]);
        const float e1 = __expf(acc[m][1][j]);
        rs[m * 4 + j] += e0 + e1;
        cs0 += e0; cs1 += e1;
      }
    if (rb != cb) {                  // diagonal tile: row sums suffice
      cs0 += __shfl_xor(cs0, 16, 64); cs0 += __shfl_xor(cs0, 32, 64);
      cs1 += __shfl_xor(cs1, 16, 64); cs1 += __shfl_xor(cs1, 32, 64);
      if (lane < 16) {
        float* dst = pcol + (size_t)(2 * rb + wr) * N_ROWS
                   + (size_t)cb * 128 + wc * 64 + nh * 32 + lane;
        dst[0]  = cs0;               // n=0 cols
        dst[16] = cs1;               // n=1 cols
      }
    }
  }

  // ---- row-sum reduce: 16 col-lanes, then across wc via LDS ----
#pragma unroll
  for (int i = 0; i < 16; ++i) {
    float v = rs[i];
    v += __shfl_xor(v, 1, 64);
    v += __shfl_xor(v, 2, 64);
    v += __shfl_xor(v, 4, 64);
    v += __shfl_xor(v, 8, 64);
    rs[i] = v;
  }
  __syncthreads();                   // all B reads done; LDS reusable
  float* redr = reinterpret_cast<float*>(ldsb);   // [2(wc)][128]
  if ((lane & 15) == 0) {
    const int g = lane >> 4;
#pragma unroll
    for (int i = 0; i < 16; ++i)
      redr[wc * 128 + wr * 64 + (i >> 2) * 16 + g * 4 + (i & 3)] = rs[i];
  }
  __syncthreads();
  if (tid < 128)
    prow[(size_t)cb * N_ROWS + (size_t)rb * 128 + tid] =
        redr[tid] + redr[128 + tid];
}

// ------------- kernel 3a: per-panel loss partials --------------------------
// Panel p, row r: sum prow[cb][r] for cb=0..p and pcol[2rb+{0,1}][r] for
// rb=p+1..63 — exactly the written slots, no zero-init needed.
__global__ __launch_bounds__(128) void nt_finalize1(
    const float* __restrict__ prow, const float* __restrict__ pcol,
    const float* __restrict__ picked_cross, float* __restrict__ loss_part) {
  const int p = blockIdx.x, tid = threadIdx.x;
  const int r = p * 128 + tid;
  float s = 0.f;
  for (int cb = 0; cb <= p; ++cb) s += prow[(size_t)cb * N_ROWS + r];
  for (int rb = p + 1; rb < NPANEL; ++rb) {
    s += pcol[(size_t)(2 * rb) * N_ROWS + r];
    s += pcol[(size_t)(2 * rb + 1) * N_ROWS + r];
  }
  const float pick = (r < B_ROWS) ? 2.0f : picked_cross[r - B_ROWS];
  float local = __logf(s) - pick;
#pragma unroll
  for (int m = 1; m < 64; m <<= 1) local += __shfl_xor(local, m, 64);
  __shared__ float red[2];
  if ((tid & 63) == 0) red[tid >> 6] = local;
  __syncthreads();
  if (tid == 0) loss_part[p] = red[0] + red[1];
}

// ------------- kernel 3b: final mean ---------------------------------------
__global__ __launch_bounds__(64) void nt_finalize2(
    const float* __restrict__ loss_part, float* __restrict__ out) {
  const int tid = threadIdx.x;
  float v = loss_part[tid];
#pragma unroll
  for (int m = 1; m < 64; m <<= 1) v += __shfl_xor(v, m, 64);
  if (tid == 0) out[0] = v / (float)N_ROWS;
}

// ---------------------------------------------------------------------------
extern "C" void kernel_launch(void* const* d_in, const int* in_sizes, int n_in,
                              void* d_out, int out_size, void* d_ws, size_t ws_size,
                              hipStream_t stream) {
  const float* f1 = (const float*)d_in[0];
  const float* f2 = (const float*)d_in[1];
  float* out = (float*)d_out;

  char* ws = (char*)d_ws;
  unsigned short* G   = (unsigned short*)ws;                         // 4 MB
  float* prow         = (float*)(ws + (size_t)4 * 1024 * 1024);      // 2 MB
  float* pcol         = (float*)(ws + (size_t)6 * 1024 * 1024);      // 4 MB
  float* picked_cross = (float*)(ws + (size_t)10 * 1024 * 1024);     // 16 KB
  float* loss_part    = (float*)(ws + (size_t)10 * 1024 * 1024 + 64 * 1024);

  hipLaunchKernelGGL(nt_norm_picked, dim3(B_ROWS / 2), dim3(256), 0, stream,
                     f1, f2, G, picked_cross);
  hipLaunchKernelGGL(nt_gemm_tile, dim3(NTRI), dim3(256), 0, stream,
                     G, prow, pcol);
  hipLaunchKernelGGL(nt_finalize1, dim3(NPANEL), dim3(128), 0, stream,
                     prow, pcol, picked_cross, loss_part);
  hipLaunchKernelGGL(nt_finalize2, dim3(1), dim3(64), 0, stream,
                     loss_part, out);
}

// Round 5
// 59.892 us; speedup vs baseline: 1.2908x; 1.2908x over previous
//
#include <hip/hip_runtime.h>
#include <hip/hip_bf16.h>
#include <math.h>

// ---------------------------------------------------------------------------
// NTXentLoss fused, symmetric triangle, persistent strip-pair version.
// loss = mean(lse(logits) - picked), logits = G G^T, G = sqrt(2)*f/||f||.
// 512 blocks = 32 rb-pairs (rb, 63-rb) x 16 splits; each pair = 130 uniform
// 128x64 subtiles (strip rb: 64-col subtiles sb=0..2rb+1), split 16 ways.
// Per block: R1-style pipeline -- A slice per wave in 64 VGPRs (32 rows),
// B subtiles (32 KB) double-buffered via global_load_lds, 1 barrier/subtile.
// Row-sums -> prow[k] (flushed at strip end; prow zero-init'd in norm);
// col-sums -> pcol[4rb+wid] per subtile (writer-unique, no init needed).
// picked[i<B] = 2 exactly; picked[i>=B] computed fp32 at normalize time.
// ---------------------------------------------------------------------------

#define B_ROWS 4096
#define D_DIM  256
#define N_ROWS 8192
#define NPANEL 64

typedef __attribute__((ext_vector_type(8))) short short8;
typedef __attribute__((ext_vector_type(4))) float f32x4;

// ---------------- kernel 1: normalize + picked + prow zero-init ------------
__global__ __launch_bounds__(256) void nt_norm_picked(
    const float* __restrict__ f1, const float* __restrict__ f2,
    unsigned short* __restrict__ G, float* __restrict__ picked_cross,
    float* __restrict__ prow) {
  __shared__ float4 vbuf[2][64];
  __shared__ float ssbuf[2];
  const int tid = threadIdx.x, lane = tid & 63, w = tid >> 6;
  // zero prow: 16*8192 floats = 32768 float4
  const int zidx = blockIdx.x * 256 + tid;
  if (zidx < 32768) reinterpret_cast<float4*>(prow)[zidx] = float4{0.f, 0.f, 0.f, 0.f};
  const int pl = w >> 1, src = w & 1;
  const int p = blockIdx.x * 2 + pl;               // pair index 0..B-1
  const float* rowp = (src == 0 ? f1 : f2) + (size_t)p * D_DIM;
  float4 v = reinterpret_cast<const float4*>(rowp)[lane];
  float ss = v.x * v.x + v.y * v.y + v.z * v.z + v.w * v.w;
#pragma unroll
  for (int m = 1; m < 64; m <<= 1) ss += __shfl_xor(ss, m, 64);
  const float scale = 1.41421356237309515f * rsqrtf(fmaxf(ss, 1e-30f));
  union { ushort4 u; __hip_bfloat16 h[4]; } pk;
  pk.h[0] = __float2bfloat16(v.x * scale);
  pk.h[1] = __float2bfloat16(v.y * scale);
  pk.h[2] = __float2bfloat16(v.z * scale);
  pk.h[3] = __float2bfloat16(v.w * scale);
  const int grow = p + src * B_ROWS;
  reinterpret_cast<ushort4*>(G + (size_t)grow * D_DIM)[lane] = pk.u;
  if (src == 0) { vbuf[pl][lane] = v; if (lane == 0) ssbuf[pl] = ss; }
  __syncthreads();
  if (src == 1) {
    float4 u = vbuf[pl][lane];
    float d = v.x * u.x + v.y * u.y + v.z * u.z + v.w * u.w;
#pragma unroll
    for (int m = 1; m < 64; m <<= 1) d += __shfl_xor(d, m, 64);
    if (lane == 0)
      picked_cross[p] = 2.0f * d * rsqrtf(ss) * rsqrtf(ssbuf[pl]);
  }
}

// ------------- staging helper: contiguous global -> LDS, swizzled ----------
// LDS[o] = G[base + swz(o)], swz(o) = o ^ (((o>>9)&7)<<4)  (row stride 512 B).
__device__ __forceinline__ void stage_lds(const char* gsrc_base, char* lds_base,
                                          int tid) {
  const int lane = tid & 63, wid = tid >> 6;
#pragma unroll
  for (int r = 0; r < 8; ++r) {
    const int o  = r * 4096 + wid * 1024 + lane * 16;
    const int so = o ^ (((o >> 9) & 7) << 4);
    __builtin_amdgcn_global_load_lds(
        (const __attribute__((address_space(1))) void*)(gsrc_base + so),
        (__attribute__((address_space(3))) void*)(lds_base + r * 4096 + wid * 1024),
        16, 0, 0);
  }
}

// -------- kernel 2: persistent strip-pair GEMM + fused exp sums ------------
// block 256 thr = 4 waves; wave owns 32 rows (wid*32..) of the 128-row strip.
__global__ __launch_bounds__(256, 2) void nt_gemm_tri(
    const unsigned short* __restrict__ G,
    float* __restrict__ prow,   // [16][N_ROWS], zero-init'd
    float* __restrict__ pcol)   // [4*NPANEL][N_ROWS], writer-covered
{
  const int bid = blockIdx.x;          // 0..511
  const int p   = bid & 31;            // pair: strips rbA=63-p and rbB=p
  const int k   = bid >> 5;            // split 0..15
  const int rbA = 63 - p;
  const int n1  = 2 * (rbA + 1);       // subtiles in strip A
  const int t0  = (130 * k) >> 4;
  const int t1  = (130 * (k + 1)) >> 4;

  const int tid = threadIdx.x, lane = tid & 63, wid = tid >> 6;
  const int l15 = lane & 15, q16 = (lane >> 4) << 4;

  __shared__ short8 lds8[4096];        // 64 KB = 2 x 32 KB B buffers
  char* ldsb = reinterpret_cast<char*>(lds8);
  const char* gb = reinterpret_cast<const char*>(G);

  short8 af[2][8];                     // 64 VGPR: 32-row A slice, K=256
  int rb = (t0 < n1) ? rbA : p;
  {
    const int sb0 = (t0 < n1) ? t0 : t0 - n1;
    stage_lds(gb + (size_t)sb0 * 32768, ldsb, tid);
  }
#pragma unroll
  for (int m = 0; m < 2; ++m) {
    const size_t ro = (size_t)(rb * 128 + wid * 32 + m * 16 + l15) * 512;
#pragma unroll
    for (int ks = 0; ks < 8; ++ks)
      af[m][ks] = *reinterpret_cast<const short8*>(gb + ro + ks * 64 + q16);
  }
  float rs[8];
#pragma unroll
  for (int i = 0; i < 8; ++i) rs[i] = 0.f;
  __syncthreads();

  for (int t = t0; t < t1; ++t) {
    char* bbuf = ldsb + ((t - t0) & 1) * 32768;
    if (t + 1 < t1) {
      const int sbn = (t + 1 < n1) ? t + 1 : t + 1 - n1;
      stage_lds(gb + (size_t)sbn * 32768, ldsb + ((t + 1 - t0) & 1) * 32768, tid);
    }
    const int sb = (t < n1) ? t : t - n1;

    f32x4 acc[2][4] = {};
#pragma unroll
    for (int ks = 0; ks < 8; ++ks) {
      short8 bf[4];
#pragma unroll
      for (int n = 0; n < 4; ++n) {
        const int brow = n * 16 + l15;
        const int off  = (brow * 512 + ks * 64 + q16) ^ ((brow & 7) << 4);
        bf[n] = *reinterpret_cast<const short8*>(bbuf + off);
      }
#pragma unroll
      for (int m = 0; m < 2; ++m)
#pragma unroll
        for (int n = 0; n < 4; ++n)
          acc[m][n] = __builtin_amdgcn_mfma_f32_16x16x32_bf16(
              af[m][ks], bf[n], acc[m][n], 0, 0, 0);
    }

    // exp + sums. acc row = wid*32+m*16+(lane>>4)*4+j, col = sb*64+n*16+l15.
    float cs[4] = {0.f, 0.f, 0.f, 0.f};
#pragma unroll
    for (int m = 0; m < 2; ++m)
#pragma unroll
      for (int n = 0; n < 4; ++n)
#pragma unroll
        for (int j = 0; j < 4; ++j) {
          const float e = __expf(acc[m][n][j]);
          rs[m * 4 + j] += e;
          cs[n] += e;
        }
    if ((sb >> 1) != rb) {             // off-diagonal: store col sums
#pragma unroll
      for (int n = 0; n < 4; ++n) {
        float c = cs[n];
        c += __shfl_xor(c, 16, 64);
        c += __shfl_xor(c, 32, 64);
        if (lane < 16)
          pcol[(size_t)(4 * rb + wid) * N_ROWS + sb * 64 + n * 16 + lane] = c;
      }
    }

    const bool last = (t + 1 == t1);
    const bool swi  = (t + 1 == n1) && !last;
    if (last || swi) {                 // flush row sums for this strip
#pragma unroll
      for (int i = 0; i < 8; ++i) {
        float v = rs[i];
        v += __shfl_xor(v, 1, 64);
        v += __shfl_xor(v, 2, 64);
        v += __shfl_xor(v, 4, 64);
        v += __shfl_xor(v, 8, 64);
        rs[i] = v;
      }
      if (l15 == 0) {
        const int g = lane >> 4;
#pragma unroll
        for (int i = 0; i < 8; ++i)
          prow[(size_t)k * N_ROWS + rb * 128 + wid * 32 + (i >> 2) * 16 + g * 4 + (i & 3)] = rs[i];
      }
#pragma unroll
      for (int i = 0; i < 8; ++i) rs[i] = 0.f;
    }
    if (swi) {                         // switch to strip B: reload A slice
      rb = p;
#pragma unroll
      for (int m = 0; m < 2; ++m) {
        const size_t ro = (size_t)(rb * 128 + wid * 32 + m * 16 + l15) * 512;
#pragma unroll
        for (int ks = 0; ks < 8; ++ks)
          af[m][ks] = *reinterpret_cast<const short8*>(gb + ro + ks * 64 + q16);
      }
    }
    __syncthreads();                   // drains DMA(t+1) + A reload + stores
  }
}

// ------------- kernel 3a: per-panel loss partials --------------------------
__global__ __launch_bounds__(128) void nt_finalize1(
    const float* __restrict__ prow, const float* __restrict__ pcol,
    const float* __restrict__ picked_cross, float* __restrict__ loss_part) {
  const int q = blockIdx.x, tid = threadIdx.x;
  const int r = q * 128 + tid;
  float s = 0.f;
#pragma unroll
  for (int j = 0; j < 16; ++j) s += prow[(size_t)j * N_ROWS + r];
  for (int rb = q + 1; rb < NPANEL; ++rb) {
    const float* b = pcol + (size_t)(4 * rb) * N_ROWS + r;
    s += b[0] + b[(size_t)N_ROWS] + b[(size_t)2 * N_ROWS] + b[(size_t)3 * N_ROWS];
  }
  const float pick = (r < B_ROWS) ? 2.0f : picked_cross[r - B_ROWS];
  float local = __logf(s) - pick;
#pragma unroll
  for (int m = 1; m < 64; m <<= 1) local += __shfl_xor(local, m, 64);
  __shared__ float red[2];
  if ((tid & 63) == 0) red[tid >> 6] = local;
  __syncthreads();
  if (tid == 0) loss_part[q] = red[0] + red[1];
}

// ------------- kernel 3b: final mean ---------------------------------------
__global__ __launch_bounds__(64) void nt_finalize2(
    const float* __restrict__ loss_part, float* __restrict__ out) {
  const int tid = threadIdx.x;
  float v = loss_part[tid];
#pragma unroll
  for (int m = 1; m < 64; m <<= 1) v += __shfl_xor(v, m, 64);
  if (tid == 0) out[0] = v / (float)N_ROWS;
}

// ---------------------------------------------------------------------------
extern "C" void kernel_launch(void* const* d_in, const int* in_sizes, int n_in,
                              void* d_out, int out_size, void* d_ws, size_t ws_size,
                              hipStream_t stream) {
  const float* f1 = (const float*)d_in[0];
  const float* f2 = (const float*)d_in[1];
  float* out = (float*)d_out;

  char* ws = (char*)d_ws;
  unsigned short* G   = (unsigned short*)ws;                          // 4 MB
  float* prow         = (float*)(ws + (size_t)4 * 1024 * 1024);       // 512 KB
  float* pcol         = (float*)(ws + (size_t)5 * 1024 * 1024);       // 8 MB
  float* picked_cross = (float*)(ws + (size_t)13 * 1024 * 1024);      // 16 KB
  float* loss_part    = (float*)(ws + (size_t)13 * 1024 * 1024 + 64 * 1024);

  hipLaunchKernelGGL(nt_norm_picked, dim3(B_ROWS / 2), dim3(256), 0, stream,
                     f1, f2, G, picked_cross, prow);
  hipLaunchKernelGGL(nt_gemm_tri, dim3(512), dim3(256), 0, stream,
                     G, prow, pcol);
  hipLaunchKernelGGL(nt_finalize1, dim3(NPANEL), dim3(128), 0, stream,
                     prow, pcol, picked_cross, loss_part);
  hipLaunchKernelGGL(nt_finalize2, dim3(1), dim3(64), 0, stream,
                     loss_part, out);
}

// Round 7
// 58.798 us; speedup vs baseline: 1.3149x; 1.0186x over previous
//
#include <hip/hip_runtime.h>
#include <hip/hip_bf16.h>
#include <math.h>

// ---------------------------------------------------------------------------
// NTXentLoss fused, symmetric triangle, strip-pair + R1 wave-tile version.
// loss = mean(lse(logits) - picked), logits = G G^T, G = sqrt(2)*f/||f||.
// 512 blocks = 32 strip-pairs (rbA=63-p, rbB=p) x 16 splits; pair = 130
// uniform 128x64 subtiles. Wave tile 64x32 (M_rep=4 -> 4 MFMA per ds_read).
// B subtiles double-buffered (2x32 KB) via global_load_lds, XOR-swizzled.
// Row-sums -> prow[k] via atomicAdd (2 adds/slot: wc=0 + wc=1 waves; FP-add
// of 2 values into zeroed slot is order-independent -> deterministic).
// Col-sums -> pcol[2*rb+wr] (column-disjoint across wc; writer-unique).
// af pinned in VGPRs via empty asm (blocks rematerialization from global).
// picked[i<B] = 2 exactly; picked[i>=B] computed fp32 at normalize time.
// ---------------------------------------------------------------------------

#define B_ROWS 4096
#define D_DIM  256
#define N_ROWS 8192
#define NPANEL 64

typedef __attribute__((ext_vector_type(8))) short short8;
typedef __attribute__((ext_vector_type(4))) float f32x4;

// ---------------- kernel 1: normalize + picked + prow zero-init ------------
__global__ __launch_bounds__(256) void nt_norm_picked(
    const float* __restrict__ f1, const float* __restrict__ f2,
    unsigned short* __restrict__ G, float* __restrict__ picked_cross,
    float* __restrict__ prow) {
  __shared__ float4 vbuf[2][64];
  __shared__ float ssbuf[2];
  const int tid = threadIdx.x, lane = tid & 63, w = tid >> 6;
  // zero prow: 16*8192 floats = 32768 float4 (grid 2048 covers)
  const int zidx = blockIdx.x * 256 + tid;
  if (zidx < 32768) reinterpret_cast<float4*>(prow)[zidx] = float4{0.f, 0.f, 0.f, 0.f};
  const int pl = w >> 1, src = w & 1;
  const int p = blockIdx.x * 2 + pl;               // pair index 0..B-1
  const float* rowp = (src == 0 ? f1 : f2) + (size_t)p * D_DIM;
  float4 v = reinterpret_cast<const float4*>(rowp)[lane];
  float ss = v.x * v.x + v.y * v.y + v.z * v.z + v.w * v.w;
#pragma unroll
  for (int m = 1; m < 64; m <<= 1) ss += __shfl_xor(ss, m, 64);
  const float scale = 1.41421356237309515f * rsqrtf(fmaxf(ss, 1e-30f));
  union { ushort4 u; __hip_bfloat16 h[4]; } pk;
  pk.h[0] = __float2bfloat16(v.x * scale);
  pk.h[1] = __float2bfloat16(v.y * scale);
  pk.h[2] = __float2bfloat16(v.z * scale);
  pk.h[3] = __float2bfloat16(v.w * scale);
  const int grow = p + src * B_ROWS;
  reinterpret_cast<ushort4*>(G + (size_t)grow * D_DIM)[lane] = pk.u;
  if (src == 0) { vbuf[pl][lane] = v; if (lane == 0) ssbuf[pl] = ss; }
  __syncthreads();
  if (src == 1) {
    float4 u = vbuf[pl][lane];
    float d = v.x * u.x + v.y * u.y + v.z * u.z + v.w * u.w;
#pragma unroll
    for (int m = 1; m < 64; m <<= 1) d += __shfl_xor(d, m, 64);
    if (lane == 0)
      picked_cross[p] = 2.0f * d * rsqrtf(ss) * rsqrtf(ssbuf[pl]);
  }
}

// ------------- staging helper: contiguous global -> LDS, swizzled ----------
// LDS[o] = G[base + swz(o)], swz(o) = o ^ (((o>>9)&7)<<4)  (row stride 512 B).
__device__ __forceinline__ void stage_lds(const char* gsrc_base, char* lds_base,
                                          int tid) {
  const int lane = tid & 63, wid = tid >> 6;
#pragma unroll
  for (int r = 0; r < 8; ++r) {
    const int o  = r * 4096 + wid * 1024 + lane * 16;
    const int so = o ^ (((o >> 9) & 7) << 4);
    __builtin_amdgcn_global_load_lds(
        (const __attribute__((address_space(1))) void*)(gsrc_base + so),
        (__attribute__((address_space(3))) void*)(lds_base + r * 4096 + wid * 1024),
        16, 0, 0);
  }
}

// -------- kernel 2: strip-pair GEMM, wave tile 64x32, fused exp sums -------
__global__ __launch_bounds__(256, 2) void nt_gemm_tri(
    const unsigned short* __restrict__ G,
    float* __restrict__ prow,   // [16][N_ROWS], zero-init'd, atomicAdd target
    float* __restrict__ pcol)   // [2*NPANEL][N_ROWS], writer-covered
{
  const int bid = blockIdx.x;          // 0..511
  const int p   = bid & 31;            // pair: strips rbA=63-p, rbB=p
  const int k   = bid >> 5;            // split 0..15
  const int rbA = 63 - p;
  const int n1  = 2 * (rbA + 1);       // subtiles in strip A
  const int t0  = (130 * k) >> 4;
  const int t1  = (130 * (k + 1)) >> 4;

  const int tid = threadIdx.x, lane = tid & 63, wid = tid >> 6;
  const int wr = wid >> 1, wc = wid & 1;     // 64-row half / 32-col half
  const int l15 = lane & 15, q16 = (lane >> 4) << 4;

  __shared__ short8 lds8[4096];        // 64 KB = 2 x 32 KB B buffers
  char* ldsb = reinterpret_cast<char*>(lds8);
  const char* gb = reinterpret_cast<const char*>(G);

  int rb = (t0 < n1) ? rbA : p;
  stage_lds(gb + (t0 < n1 ? t0 : t0 - n1) * 32768, ldsb, tid);

  short8 af[4][8];                     // 64 rows x K=256 slice of A
#pragma unroll
  for (int m = 0; m < 4; ++m) {
    const int ro = (rb * 128 + wr * 64 + m * 16 + l15) * 512;
#pragma unroll
    for (int ks = 0; ks < 8; ++ks) {
      af[m][ks] = *reinterpret_cast<const short8*>(gb + ro + ks * 64 + q16);
      asm volatile("" : "+v"(af[m][ks]));   // pin: block rematerialization
    }
  }
  float rs[16];
#pragma unroll
  for (int i = 0; i < 16; ++i) rs[i] = 0.f;
  __syncthreads();

  for (int t = t0; t < t1; ++t) {
    char* bbuf = ldsb + ((t - t0) & 1) * 32768;
    if (t + 1 < t1) {
      const int sbn = (t + 1 < n1) ? t + 1 : t + 1 - n1;
      stage_lds(gb + sbn * 32768, ldsb + ((t + 1 - t0) & 1) * 32768, tid);
    }
    const int sb = (t < n1) ? t : t - n1;

    f32x4 acc[4][2] = {};
#pragma unroll
    for (int ks = 0; ks < 8; ++ks) {
      short8 bf[2];
#pragma unroll
      for (int n = 0; n < 2; ++n) {
        const int brow = wc * 32 + n * 16 + l15;
        const int off  = (brow * 512 + ks * 64 + q16) ^ ((brow & 7) << 4);
        bf[n] = *reinterpret_cast<const short8*>(bbuf + off);
      }
#pragma unroll
      for (int m = 0; m < 4; ++m)
#pragma unroll
        for (int n = 0; n < 2; ++n)
          acc[m][n] = __builtin_amdgcn_mfma_f32_16x16x32_bf16(
              af[m][ks], bf[n], acc[m][n], 0, 0, 0);
    }

    // exp + sums. acc row = wr*64+m*16+(lane>>4)*4+j, col = sb*64+wc*32+n*16+l15.
    float cs0 = 0.f, cs1 = 0.f;
#pragma unroll
    for (int m = 0; m < 4; ++m)
#pragma unroll
      for (int j = 0; j < 4; ++j) {
        const float e0 = __expf(acc[m][0][j]);
        const float e1 = __expf(acc[m][1][j]);
        rs[m * 4 + j] += e0 + e1;
        cs0 += e0; cs1 += e1;
      }
    if ((sb >> 1) != rb) {             // off-diagonal: store col sums
      cs0 += __shfl_xor(cs0, 16, 64); cs0 += __shfl_xor(cs0, 32, 64);
      cs1 += __shfl_xor(cs1, 16, 64); cs1 += __shfl_xor(cs1, 32, 64);
      if (lane < 16) {
        float* dst = pcol + (size_t)(2 * rb + wr) * N_ROWS + sb * 64 + wc * 32 + lane;
        dst[0]  = cs0;                 // n=0 cols
        dst[16] = cs1;                 // n=1 cols
      }
    }

    const bool last = (t + 1 == t1);
    const bool swi  = (t + 1 == n1) && !last;
    if (last || swi) {                 // flush row sums (atomic: wc=0 + wc=1)
#pragma unroll
      for (int i = 0; i < 16; ++i) {
        float v = rs[i];
        v += __shfl_xor(v, 1, 64);
        v += __shfl_xor(v, 2, 64);
        v += __shfl_xor(v, 4, 64);
        v += __shfl_xor(v, 8, 64);
        rs[i] = v;
      }
      if (l15 == 0) {
        const int g = lane >> 4;
#pragma unroll
        for (int i = 0; i < 16; ++i)
          atomicAdd(&prow[(size_t)k * N_ROWS + rb * 128 + wr * 64 +
                          (i >> 2) * 16 + g * 4 + (i & 3)], rs[i]);
      }
#pragma unroll
      for (int i = 0; i < 16; ++i) rs[i] = 0.f;
    }
    if (swi) {                         // switch to strip B: reload A slice
      rb = p;
#pragma unroll
      for (int m = 0; m < 4; ++m) {
        const int ro = (rb * 128 + wr * 64 + m * 16 + l15) * 512;
#pragma unroll
        for (int ks = 0; ks < 8; ++ks) {
          af[m][ks] = *reinterpret_cast<const short8*>(gb + ro + ks * 64 + q16);
          asm volatile("" : "+v"(af[m][ks]));
        }
      }
    }
    __syncthreads();                   // buf(t+1) resident; buf(t) reads done
  }
}

// ------------- kernel 3a: per-64-row loss partials (4-way slot split) ------
__global__ __launch_bounds__(256) void nt_finalize1(
    const float* __restrict__ prow, const float* __restrict__ pcol,
    const float* __restrict__ picked_cross, float* __restrict__ loss_part) {
  const int blk = blockIdx.x, tid = threadIdx.x;   // 128 blocks x 256 thr
  const int pan = blk >> 1;                        // 128-row panel
  const int l   = tid & 63;
  const int r   = pan * 128 + (blk & 1) * 64 + l;
  const int g   = tid >> 6;                        // 4 slot groups
  float s = 0.f;
  if (g == 0) {
#pragma unroll
    for (int j = 0; j < 16; ++j) s += prow[(size_t)j * N_ROWS + r];
  } else {
    for (int rb = pan + g; rb < NPANEL; rb += 3) {   // rb = pan+1..63, 3-way
      s += pcol[(size_t)(2 * rb) * N_ROWS + r];
      s += pcol[(size_t)(2 * rb + 1) * N_ROWS + r];
    }
  }
  __shared__ float red[4][64];
  red[g][l] = s;
  __syncthreads();
  if (g == 0) {
    float tot = red[0][l] + red[1][l] + red[2][l] + red[3][l];
    const float pick = (r < B_ROWS) ? 2.0f : picked_cross[r - B_ROWS];
    float local = __logf(tot) - pick;
#pragma unroll
    for (int m = 1; m < 64; m <<= 1) local += __shfl_xor(local, m, 64);
    if (l == 0) loss_part[blk] = local;
  }
}

// ------------- kernel 3b: final mean ---------------------------------------
__global__ __launch_bounds__(128) void nt_finalize2(
    const float* __restrict__ loss_part, float* __restrict__ out) {
  const int tid = threadIdx.x;
  float v = loss_part[tid];
#pragma unroll
  for (int m = 1; m < 64; m <<= 1) v += __shfl_xor(v, m, 64);
  __shared__ float red[2];
  if ((tid & 63) == 0) red[tid >> 6] = v;
  __syncthreads();
  if (tid == 0) out[0] = (red[0] + red[1]) / (float)N_ROWS;
}

// ---------------------------------------------------------------------------
extern "C" void kernel_launch(void* const* d_in, const int* in_sizes, int n_in,
                              void* d_out, int out_size, void* d_ws, size_t ws_size,
                              hipStream_t stream) {
  const float* f1 = (const float*)d_in[0];
  const float* f2 = (const float*)d_in[1];
  float* out = (float*)d_out;

  char* ws = (char*)d_ws;
  unsigned short* G   = (unsigned short*)ws;                          // 4 MB
  float* prow         = (float*)(ws + (size_t)4 * 1024 * 1024);       // 512 KB
  float* pcol         = (float*)(ws + (size_t)5 * 1024 * 1024);       // 4 MB
  float* picked_cross = (float*)(ws + (size_t)9 * 1024 * 1024);       // 16 KB
  float* loss_part    = (float*)(ws + (size_t)9 * 1024 * 1024 + 64 * 1024);

  hipLaunchKernelGGL(nt_norm_picked, dim3(B_ROWS / 2), dim3(256), 0, stream,
                     f1, f2, G, picked_cross, prow);
  hipLaunchKernelGGL(nt_gemm_tri, dim3(512), dim3(256), 0, stream,
                     G, prow, pcol);
  hipLaunchKernelGGL(nt_finalize1, dim3(128), dim3(256), 0, stream,
                     prow, pcol, picked_cross, loss_part);
  hipLaunchKernelGGL(nt_finalize2, dim3(1), dim3(128), 0, stream,
                     loss_part, out);
}